// Round 19
// baseline (95.364 us; speedup 1.0000x reference)
//
#include <hip/hip_runtime.h>
#include <hip/hip_bf16.h>
#include <math.h>

// BahdanauAttention: B=32, T=2048, D=512, U=512, fp32 in/out.
#define BB 32
#define TT 2048
#define DD 512
#define UU 512

typedef __attribute__((ext_vector_type(8))) short short8v;     // MFMA bf16 A/B frag
typedef __attribute__((ext_vector_type(4))) float floatx4;     // MFMA C/D frag
typedef __attribute__((ext_vector_type(8))) unsigned short ushort8v;
typedef __attribute__((ext_vector_type(4))) unsigned short ushort4v;

static __device__ inline unsigned short f2bf(float f) {
  __hip_bfloat16 h = __float2bfloat16(f);
  return *reinterpret_cast<unsigned short*>(&h);
}

static __device__ inline float fast_tanh(float x) {
  x = fminf(fmaxf(x, -15.f), 15.f);
  float e2 = __expf(2.f * x);
  return (e2 - 1.f) * __builtin_amdgcn_rcpf(e2 + 1.f);
}

// ---------------------------------------------------------------------------
// K0: W1[k][u] fp32 -> w1a blocked bf16 [kt(16)][kg(4)][u(512)][8]
// (layout verified r7-r18). grid (16 kt, 4 uc), block 256.
// ---------------------------------------------------------------------------
__global__ __launch_bounds__(256) void pack_w1a_kernel(
    const float* __restrict__ W1, unsigned short* __restrict__ w1a) {
  __shared__ float Wf[32][132];
  const int kt = blockIdx.x, uc = blockIdx.y;
  const int tid = threadIdx.x;
  {
    const int k = tid >> 3;
    const int u16 = (tid & 7) * 16;
    const float* src = W1 + (size_t)(kt * 32 + k) * UU + uc * 128 + u16;
    #pragma unroll
    for (int q = 0; q < 4; ++q) {
      const float4 v = *(const float4*)(src + q * 4);
      Wf[k][u16 + q * 4 + 0] = v.x;
      Wf[k][u16 + q * 4 + 1] = v.y;
      Wf[k][u16 + q * 4 + 2] = v.z;
      Wf[k][u16 + q * 4 + 3] = v.w;
    }
  }
  __syncthreads();
  unsigned short* dst = w1a + (size_t)kt * 16384;  // 32 KB per kt
  #pragma unroll
  for (int s = 0; s < 2; ++s) {
    const int c = s * 256 + tid;
    const int kg = c >> 7;
    const int u = c & 127;
    ushort8v o;
    #pragma unroll
    for (int e = 0; e < 8; ++e) o[e] = f2bf(Wf[kg * 8 + e][u]);
    *(ushort8v*)(dst + ((size_t)kg * 512 + uc * 128 + u) * 8) = o;
  }
}

// ---------------------------------------------------------------------------
// K1: qb[b,u] = query[b,:] @ W2[:,u] + b2[u] + b1[u]
// ---------------------------------------------------------------------------
__global__ __launch_bounds__(256) void projq_kernel(
    const float* __restrict__ query, const float* __restrict__ W2,
    const float* __restrict__ b2, const float* __restrict__ b1,
    float* __restrict__ qb) {
  int b = blockIdx.x;
  int u = blockIdx.y * 256 + threadIdx.x;
  float acc = b2[u] + b1[u];
  const float* q = query + b * DD;
  #pragma unroll 16
  for (int d = 0; d < DD; ++d) acc += q[d] * W2[(size_t)d * UU + u];
  qb[b * UU + u] = acc;
}

// ---------------------------------------------------------------------------
// K2: FUSED score+context kernel — r16 structure, SPILL-FREE register budget.
// __launch_bounds__(512, 2): VGPR cap 256 >= ~190 live (acc 64 + af-ring 48 +
// staging 32 + addr) -> NO scratch spills. (r7-r18 all capped at 4 waves/EU
// -> VGPR 64-116 reported with 150-200 live -> accumulators spilled; the
// 10-19 MB WRITE_SIZE anomaly was scratch traffic.)
// GEMM: two-phase B staging, ring-3 dist-2 A prefetch, 3 barriers (r16).
// Tail: no-max-shift fused softmax/context partials (r16, verified).
// ---------------------------------------------------------------------------
#define SBM 64

__global__ __launch_bounds__(512, 2) void score_fused_kernel(
    const float* __restrict__ values, const unsigned short* __restrict__ w1a,
    const float* __restrict__ qb, const float* __restrict__ V,
    float* __restrict__ score, float* __restrict__ o_part,
    float* __restrict__ l_part) {
  __shared__ __align__(16) unsigned short Bp[2][8][4][SBM][8];  // 64 KB
  __shared__ float qv_lds[512];
  __shared__ float vv_lds[512];
  __shared__ float part[8][SBM];
  __shared__ float sw[SBM];          // exp(score) per row
  __shared__ float opart[4][512];    // 8 KB

  const int tid = threadIdx.x;
  const int row0 = blockIdx.x * SBM;
  const int b = row0 >> 11;           // row0 / TT
  const int lane = tid & 63;
  const int wid = tid >> 6;           // 8 waves -> u slice
  const int wu = wid * 64;
  const int fr = lane & 15;
  const int kg = lane >> 4;

  qv_lds[tid] = qb[b * UU + tid];     // b1,b2 folded into qb
  vv_lds[tid] = V[tid];

  // staging geometry: thread owns (row sm, k-quad sj); kt-local stride 2048 us
  const int sm = tid >> 3;
  const int sj = tid & 7;
  const float* bsrc = values + (size_t)(row0 + sm) * DD + sj * 4;
  const int bofs = (sj >> 1) * (SBM * 8) + sm * 8 + (sj & 1) * 4;

  // ---- stage half-0 (kt 0..7) ----
  {
    float4 r0[8];
    #pragma unroll
    for (int q = 0; q < 8; ++q)
      r0[q] = *(const float4*)(bsrc + (size_t)q * 32);
    #pragma unroll
    for (int q = 0; q < 8; ++q) {
      ushort4v o = {f2bf(r0[q].x), f2bf(r0[q].y), f2bf(r0[q].z), f2bf(r0[q].w)};
      *(ushort4v*)(&Bp[0][q][0][0][0] + bofs) = o;
    }
  }

  // ---- A-frag prefetch ring (distance 2): prologue A(0), A(1) ----
  const size_t aofs = (size_t)(kg * 512 + wu + fr) * 8;
  short8v af[3][4];
  #pragma unroll
  for (int ju = 0; ju < 4; ++ju) {
    af[0][ju] = *(const short8v*)(w1a + aofs + (size_t)ju * 128);
    af[1][ju] = *(const short8v*)(w1a + 16384 + aofs + (size_t)ju * 128);
  }

  __syncthreads();  // barrier 1: half-0 visible

  // ---- issue ALL half-1 loads now; consumed after step 7 ----
  float4 r1[8];
  #pragma unroll
  for (int q = 0; q < 8; ++q)
    r1[q] = *(const float4*)(bsrc + (size_t)(8 + q) * 32);

  floatx4 acc[4][4] = {};  // [ju][jm]

  #pragma unroll
  for (int t = 0; t < 16; ++t) {
    if (t == 8) {
      #pragma unroll
      for (int q = 0; q < 8; ++q) {
        ushort4v o = {f2bf(r1[q].x), f2bf(r1[q].y), f2bf(r1[q].z), f2bf(r1[q].w)};
        *(ushort4v*)(&Bp[1][q][0][0][0] + bofs) = o;
      }
      __syncthreads();  // barrier 2: half-1 visible
    }

    if (t + 2 < 16) {  // prefetch A(t+2) into ring slot (t+2)%3
      #pragma unroll
      for (int ju = 0; ju < 4; ++ju)
        af[(t + 2) % 3][ju] =
            *(const short8v*)(w1a + (size_t)(t + 2) * 16384 + aofs + (size_t)ju * 128);
    }

    #pragma unroll
    for (int jm = 0; jm < 4; ++jm) {
      const short8v bfv = *(const short8v*)&Bp[t >> 3][t & 7][kg][jm * 16 + fr][0];
      #pragma unroll
      for (int ju = 0; ju < 4; ++ju)
        acc[ju][jm] = __builtin_amdgcn_mfma_f32_16x16x32_bf16(af[t % 3][ju], bfv, acc[ju][jm], 0, 0, 0);
    }
  }

  // ---- GEMM epilogue: tanh + V-weight; u on the register axis ----
  // C[u][m]: m = jm*16 + fr, u = wu + ju*16 + kg*4 + reg  [verified r7-r18]
  float pm[4] = {0.f, 0.f, 0.f, 0.f};
  #pragma unroll
  for (int ju = 0; ju < 4; ++ju) {
    const float4 qv = *(const float4*)&qv_lds[wu + ju * 16 + kg * 4];
    const float4 vv = *(const float4*)&vv_lds[wu + ju * 16 + kg * 4];
    const float qa[4] = {qv.x, qv.y, qv.z, qv.w};
    const float va[4] = {vv.x, vv.y, vv.z, vv.w};
    #pragma unroll
    for (int jm = 0; jm < 4; ++jm)
      #pragma unroll
      for (int reg = 0; reg < 4; ++reg)
        pm[jm] += fast_tanh(acc[ju][jm][reg] + qa[reg]) * va[reg];
  }
  #pragma unroll
  for (int jm = 0; jm < 4; ++jm) {
    pm[jm] += __shfl_xor(pm[jm], 16, 64);
    pm[jm] += __shfl_xor(pm[jm], 32, 64);
  }
  if (lane < 16) {
    #pragma unroll
    for (int jm = 0; jm < 4; ++jm) part[wid][jm * 16 + lane] = pm[jm];
  }
  __syncthreads();  // barrier 3: part visible
  if (tid < SBM) {
    float s = 0.f;
    #pragma unroll
    for (int w = 0; w < 8; ++w) s += part[w][tid];
    score[row0 + tid] = s;
    sw[tid] = __expf(s);   // no max-shift: |s| <= ~18, fp32-safe (r16-verified)
  }
  __syncthreads();  // barrier 4: sw visible

  // ---- fused context partial: o = sum_r exp(s_r) * values[r][:] ----
  {
    const int g = tid >> 7;          // 0..3 -> rows g*16..g*16+15
    const int dq = tid & 127;        // d = dq*4
    const float* vrow = values + (size_t)(row0 + g * 16) * DD + dq * 4;
    float4 o4 = {0.f, 0.f, 0.f, 0.f};
    #pragma unroll
    for (int r = 0; r < 16; ++r) {
      const float w = sw[g * 16 + r];
      const float4 v = *(const float4*)(vrow + (size_t)r * DD);  // L2-hot
      o4.x += w * v.x; o4.y += w * v.y; o4.z += w * v.z; o4.w += w * v.w;
    }
    *(float4*)&opart[g][dq * 4] = o4;
  }
  if (wid == 0) {  // wave 0: l = sum of the 64 exp(s)
    float lv = sw[lane];
    #pragma unroll
    for (int m = 1; m < 64; m <<= 1) lv += __shfl_xor(lv, m, 64);
    if (lane == 0) l_part[blockIdx.x] = lv;
  }
  __syncthreads();  // barrier 5: opart visible
  {
    const int d = tid;  // 512 threads = 512 d
    o_part[(size_t)blockIdx.x * DD + d] =
        opart[0][d] + opart[1][d] + opart[2][d] + opart[3][d];
  }
}

// ---------------------------------------------------------------------------
// K3: reduce per-chunk partials -> ctx and Linv. 32 chunks per batch.
// grid (32 b), block 128.
// ---------------------------------------------------------------------------
__global__ __launch_bounds__(128) void reduce_kernel(
    const float* __restrict__ o_part, const float* __restrict__ l_part,
    float* __restrict__ ctx, float* __restrict__ Linv) {
  const int b = blockIdx.x;
  const int d0 = threadIdx.x * 4;
  __shared__ float Ls;
  if (threadIdx.x == 0) {
    float s = 0.f;
    #pragma unroll 8
    for (int c = 0; c < 32; ++c) s += l_part[b * 32 + c];
    Ls = 1.f / s;
    Linv[b] = Ls;
  }
  float4 a = {0.f, 0.f, 0.f, 0.f};
  #pragma unroll 8
  for (int c = 0; c < 32; ++c) {
    const float4 p = *(const float4*)(o_part + (size_t)(b * 32 + c) * DD + d0);
    a.x += p.x; a.y += p.y; a.z += p.z; a.w += p.w;
  }
  __syncthreads();
  const float inv = Ls;
  a.x *= inv; a.y *= inv; a.z *= inv; a.w *= inv;
  *(float4*)(ctx + (size_t)b * DD + d0) = a;
}

// ---------------------------------------------------------------------------
// K4: attn[b,t] = exp(score[b,t]) * Linv[b]. grid 64, block 1024.
// ---------------------------------------------------------------------------
__global__ __launch_bounds__(1024) void attn_kernel(
    const float* __restrict__ score, const float* __restrict__ Linv,
    float* __restrict__ attn) {
  const int i = blockIdx.x * 1024 + threadIdx.x;
  const int b = i >> 11;
  attn[i] = __expf(score[i]) * Linv[b];
}

// ---------------------------------------------------------------------------
extern "C" void kernel_launch(void* const* d_in, const int* in_sizes, int n_in,
                              void* d_out, int out_size, void* d_ws, size_t ws_size,
                              hipStream_t stream) {
  const float* query  = (const float*)d_in[0];
  const float* values = (const float*)d_in[1];
  const float* W1     = (const float*)d_in[2];
  const float* b1     = (const float*)d_in[3];
  const float* W2     = (const float*)d_in[4];
  const float* b2     = (const float*)d_in[5];
  const float* V      = (const float*)d_in[6];
  // d_in[7] = bV: uniform score shift -> softmax-invariant, dropped.

  float* ctx  = (float*)d_out;             // [B,D]
  float* attn = (float*)d_out + BB * DD;   // [B,T,1]

  // ws: qb 64KB | score 256KB | w1a 512KB | o_part 2MB | l_part 4KB | Linv
  float* qb           = (float*)d_ws;                        // [B,U]
  float* score        = qb + BB * UU;                        // [B*T]
  unsigned short* w1a = (unsigned short*)(score + BB * TT);  // 512KB bf16
  float* o_part       = (float*)(w1a + (size_t)UU * DD);     // [1024][512]
  float* l_part       = o_part + (size_t)1024 * DD;          // [1024]
  float* Linv         = l_part + 1024;                       // [32]

  pack_w1a_kernel<<<dim3(16, 4), 256, 0, stream>>>(W1, w1a);
  projq_kernel<<<dim3(BB, UU / 256), 256, 0, stream>>>(query, W2, b2, b1, qb);

  score_fused_kernel<<<(BB * TT) / SBM, 512, 0, stream>>>(
      values, w1a, qb, V, score, o_part, l_part);

  reduce_kernel<<<BB, 128, 0, stream>>>(o_part, l_part, ctx, Linv);
  attn_kernel<<<(BB * TT) / 1024, 1024, 0, stream>>>(score, Linv, attn);
}

// Round 20
// 80.314 us; speedup vs baseline: 1.1874x; 1.1874x over previous
//
#include <hip/hip_runtime.h>
#include <hip/hip_bf16.h>
#include <math.h>

// BahdanauAttention: B=32, T=2048, D=512, U=512, fp32 in/out.
#define BB 32
#define TT 2048
#define DD 512
#define UU 512

typedef __attribute__((ext_vector_type(8))) short short8v;     // MFMA bf16 A/B frag
typedef __attribute__((ext_vector_type(4))) float floatx4;     // MFMA C/D frag
typedef __attribute__((ext_vector_type(8))) unsigned short ushort8v;
typedef __attribute__((ext_vector_type(4))) unsigned short ushort4v;

static __device__ inline unsigned short f2bf(float f) {
  __hip_bfloat16 h = __float2bfloat16(f);
  return *reinterpret_cast<unsigned short*>(&h);
}

static __device__ inline float bf2f(unsigned short u) {
  union { unsigned int i; float f; } x;
  x.i = ((unsigned int)u) << 16;
  return x.f;
}

static __device__ inline float fast_tanh(float x) {
  x = fminf(fmaxf(x, -15.f), 15.f);
  float e2 = __expf(2.f * x);
  return (e2 - 1.f) * __builtin_amdgcn_rcpf(e2 + 1.f);
}

// ---------------------------------------------------------------------------
// K0: PREP — fused pack_w1a + projq (independent work, one launch).
// blocks 0..63:  W1[k][u] fp32 -> w1a blocked bf16 [kt(16)][kg(4)][u(512)][8]
// blocks 64..127: qb[b,u] = query[b,:]@W2[:,u] + b2[u] + b1[u]
// ---------------------------------------------------------------------------
__global__ __launch_bounds__(256) void prep_kernel(
    const float* __restrict__ W1, unsigned short* __restrict__ w1a,
    const float* __restrict__ query, const float* __restrict__ W2,
    const float* __restrict__ b2, const float* __restrict__ b1,
    float* __restrict__ qb) {
  __shared__ float Wf[32][132];
  const int tid = threadIdx.x;
  if (blockIdx.x < 64) {
    const int kt = blockIdx.x & 15, uc = blockIdx.x >> 4;
    {
      const int k = tid >> 3;
      const int u16 = (tid & 7) * 16;
      const float* src = W1 + (size_t)(kt * 32 + k) * UU + uc * 128 + u16;
      #pragma unroll
      for (int q = 0; q < 4; ++q) {
        const float4 v = *(const float4*)(src + q * 4);
        Wf[k][u16 + q * 4 + 0] = v.x;
        Wf[k][u16 + q * 4 + 1] = v.y;
        Wf[k][u16 + q * 4 + 2] = v.z;
        Wf[k][u16 + q * 4 + 3] = v.w;
      }
    }
    __syncthreads();
    unsigned short* dst = w1a + (size_t)kt * 16384;  // 32 KB per kt
    #pragma unroll
    for (int s = 0; s < 2; ++s) {
      const int c = s * 256 + tid;
      const int kg = c >> 7;
      const int u = c & 127;
      ushort8v o;
      #pragma unroll
      for (int e = 0; e < 8; ++e) o[e] = f2bf(Wf[kg * 8 + e][u]);
      *(ushort8v*)(dst + ((size_t)kg * 512 + uc * 128 + u) * 8) = o;
    }
  } else {
    const int bidx = blockIdx.x - 64;
    const int b = bidx >> 1;
    const int u = (bidx & 1) * 256 + tid;
    float acc = b2[u] + b1[u];
    const float* q = query + b * DD;
    #pragma unroll 16
    for (int d = 0; d < DD; ++d) acc += q[d] * W2[(size_t)d * UU + u];
    qb[b * UU + u] = acc;
  }
}

// ---------------------------------------------------------------------------
// K2: FUSED score+context kernel — r16 structure (empirical best, 78us).
// GEMM: two-phase B staging, ring-3 dist-2 A prefetch, 3 barriers.
// NEW: context tail reads values from the LDS B-panel (bf16) instead of
// global — removes 128KB/block global re-read + its L2 pollution of w1a.
// (bf16-values context precision proven in r6: absmax stayed 4.88e-4.)
// ---------------------------------------------------------------------------
#define SBM 64

__global__ __launch_bounds__(512, 4) void score_fused_kernel(
    const float* __restrict__ values, const unsigned short* __restrict__ w1a,
    const float* __restrict__ qb, const float* __restrict__ V,
    float* __restrict__ score, float* __restrict__ o_part,
    float* __restrict__ l_part) {
  __shared__ __align__(16) unsigned short Bp[2][8][4][SBM][8];  // 64 KB
  __shared__ float qv_lds[512];
  __shared__ float vv_lds[512];
  __shared__ float part[8][SBM];
  __shared__ float sw[SBM];          // exp(score) per row
  __shared__ float opart[4][512];    // 8 KB

  const int tid = threadIdx.x;
  const int row0 = blockIdx.x * SBM;
  const int b = row0 >> 11;           // row0 / TT
  const int lane = tid & 63;
  const int wid = tid >> 6;           // 8 waves -> u slice
  const int wu = wid * 64;
  const int fr = lane & 15;
  const int kg = lane >> 4;

  qv_lds[tid] = qb[b * UU + tid];     // b1,b2 folded into qb
  vv_lds[tid] = V[tid];

  // staging geometry: thread owns (row sm, k-quad sj); kt-local stride 2048 us
  const int sm = tid >> 3;
  const int sj = tid & 7;
  const float* bsrc = values + (size_t)(row0 + sm) * DD + sj * 4;
  const int bofs = (sj >> 1) * (SBM * 8) + sm * 8 + (sj & 1) * 4;

  // ---- stage half-0 (kt 0..7) ----
  {
    float4 r0[8];
    #pragma unroll
    for (int q = 0; q < 8; ++q)
      r0[q] = *(const float4*)(bsrc + (size_t)q * 32);
    #pragma unroll
    for (int q = 0; q < 8; ++q) {
      ushort4v o = {f2bf(r0[q].x), f2bf(r0[q].y), f2bf(r0[q].z), f2bf(r0[q].w)};
      *(ushort4v*)(&Bp[0][q][0][0][0] + bofs) = o;
    }
  }

  // ---- A-frag prefetch ring (distance 2): prologue A(0), A(1) ----
  const size_t aofs = (size_t)(kg * 512 + wu + fr) * 8;
  short8v af[3][4];
  #pragma unroll
  for (int ju = 0; ju < 4; ++ju) {
    af[0][ju] = *(const short8v*)(w1a + aofs + (size_t)ju * 128);
    af[1][ju] = *(const short8v*)(w1a + 16384 + aofs + (size_t)ju * 128);
  }

  __syncthreads();  // barrier 1: half-0 visible

  // ---- issue ALL half-1 loads now; consumed after step 7 ----
  float4 r1[8];
  #pragma unroll
  for (int q = 0; q < 8; ++q)
    r1[q] = *(const float4*)(bsrc + (size_t)(8 + q) * 32);

  floatx4 acc[4][4] = {};  // [ju][jm]

  #pragma unroll
  for (int t = 0; t < 16; ++t) {
    if (t == 8) {
      #pragma unroll
      for (int q = 0; q < 8; ++q) {
        ushort4v o = {f2bf(r1[q].x), f2bf(r1[q].y), f2bf(r1[q].z), f2bf(r1[q].w)};
        *(ushort4v*)(&Bp[1][q][0][0][0] + bofs) = o;
      }
      __syncthreads();  // barrier 2: half-1 visible
    }

    if (t + 2 < 16) {  // prefetch A(t+2) into ring slot (t+2)%3
      #pragma unroll
      for (int ju = 0; ju < 4; ++ju)
        af[(t + 2) % 3][ju] =
            *(const short8v*)(w1a + (size_t)(t + 2) * 16384 + aofs + (size_t)ju * 128);
    }

    #pragma unroll
    for (int jm = 0; jm < 4; ++jm) {
      const short8v bfv = *(const short8v*)&Bp[t >> 3][t & 7][kg][jm * 16 + fr][0];
      #pragma unroll
      for (int ju = 0; ju < 4; ++ju)
        acc[ju][jm] = __builtin_amdgcn_mfma_f32_16x16x32_bf16(af[t % 3][ju], bfv, acc[ju][jm], 0, 0, 0);
    }
  }

  // ---- GEMM epilogue: tanh + V-weight; u on the register axis ----
  // C[u][m]: m = jm*16 + fr, u = wu + ju*16 + kg*4 + reg  [verified r7-r19]
  float pm[4] = {0.f, 0.f, 0.f, 0.f};
  #pragma unroll
  for (int ju = 0; ju < 4; ++ju) {
    const float4 qv = *(const float4*)&qv_lds[wu + ju * 16 + kg * 4];
    const float4 vv = *(const float4*)&vv_lds[wu + ju * 16 + kg * 4];
    const float qa[4] = {qv.x, qv.y, qv.z, qv.w};
    const float va[4] = {vv.x, vv.y, vv.z, vv.w};
    #pragma unroll
    for (int jm = 0; jm < 4; ++jm)
      #pragma unroll
      for (int reg = 0; reg < 4; ++reg)
        pm[jm] += fast_tanh(acc[ju][jm][reg] + qa[reg]) * va[reg];
  }
  #pragma unroll
  for (int jm = 0; jm < 4; ++jm) {
    pm[jm] += __shfl_xor(pm[jm], 16, 64);
    pm[jm] += __shfl_xor(pm[jm], 32, 64);
  }
  if (lane < 16) {
    #pragma unroll
    for (int jm = 0; jm < 4; ++jm) part[wid][jm * 16 + lane] = pm[jm];
  }
  __syncthreads();  // barrier 3: part visible
  if (tid < SBM) {
    float s = 0.f;
    #pragma unroll
    for (int w = 0; w < 8; ++w) s += part[w][tid];
    score[row0 + tid] = s;
    sw[tid] = __expf(s);   // no max-shift: |s| <= ~18, fp32-safe (r16-verified)
  }
  __syncthreads();  // barrier 4: sw visible

  // ---- fused context partial from the LDS B-panel (bf16 values) ----
  // d = dq*4: kt = dq>>3 (half=kt>>3, ktl=kt&7), kg = (dq>>1)&3, e = (dq&1)*4.
  {
    const int g = tid >> 7;          // 0..3 -> rows g*16..g*16+15
    const int dq = tid & 127;
    const int half = dq >> 6;        // kt>>3 = dq>>6
    const int ktl = (dq >> 3) & 7;
    const int kgl = (dq >> 1) & 3;
    const int e = (dq & 1) * 4;
    float4 o4 = {0.f, 0.f, 0.f, 0.f};
    #pragma unroll
    for (int r = 0; r < 16; ++r) {
      const int m = g * 16 + r;
      const float w = sw[m];
      const ushort4v v4 = *(const ushort4v*)&Bp[half][ktl][kgl][m][e];
      o4.x += w * bf2f(v4[0]);
      o4.y += w * bf2f(v4[1]);
      o4.z += w * bf2f(v4[2]);
      o4.w += w * bf2f(v4[3]);
    }
    *(float4*)&opart[g][dq * 4] = o4;
  }
  if (wid == 0) {  // wave 0: l = sum of the 64 exp(s)
    float lv = sw[lane];
    #pragma unroll
    for (int m = 1; m < 64; m <<= 1) lv += __shfl_xor(lv, m, 64);
    if (lane == 0) l_part[blockIdx.x] = lv;
  }
  __syncthreads();  // barrier 5: opart visible
  {
    const int d = tid;  // 512 threads = 512 d
    o_part[(size_t)blockIdx.x * DD + d] =
        opart[0][d] + opart[1][d] + opart[2][d] + opart[3][d];
  }
}

// ---------------------------------------------------------------------------
// K3: FINISH — fused reduce + attn (independent after score; one launch).
// blocks 0..31:  ctx[b,:] = (sum_c o_part)/L_b
// blocks 32..95: attn slab: attn[i] = exp(score[i]) / L_b (own L sum; 8/thread)
// ---------------------------------------------------------------------------
__global__ __launch_bounds__(128) void finish_kernel(
    const float* __restrict__ o_part, const float* __restrict__ l_part,
    const float* __restrict__ score, float* __restrict__ ctx,
    float* __restrict__ attn) {
  if (blockIdx.x < 32) {
    const int b = blockIdx.x;
    const int d0 = threadIdx.x * 4;
    float Ls = 0.f;
    #pragma unroll 8
    for (int c = 0; c < 32; ++c) Ls += l_part[b * 32 + c];
    const float inv = 1.f / Ls;
    float4 a = {0.f, 0.f, 0.f, 0.f};
    #pragma unroll 8
    for (int c = 0; c < 32; ++c) {
      const float4 p = *(const float4*)(o_part + (size_t)(b * 32 + c) * DD + d0);
      a.x += p.x; a.y += p.y; a.z += p.z; a.w += p.w;
    }
    a.x *= inv; a.y *= inv; a.z *= inv; a.w *= inv;
    *(float4*)(ctx + (size_t)b * DD + d0) = a;
  } else {
    const int c = blockIdx.x - 32;        // 64 slabs of 1024 (one half-batch)
    const int b = c >> 1;
    float Ls = 0.f;
    #pragma unroll 8
    for (int q = 0; q < 32; ++q) Ls += l_part[b * 32 + q];
    const float inv = 1.f / Ls;
    const int base = c * 1024 + threadIdx.x;
    #pragma unroll
    for (int q = 0; q < 8; ++q) {
      const int i = base + q * 128;
      attn[i] = __expf(score[i]) * inv;
    }
  }
}

// ---------------------------------------------------------------------------
extern "C" void kernel_launch(void* const* d_in, const int* in_sizes, int n_in,
                              void* d_out, int out_size, void* d_ws, size_t ws_size,
                              hipStream_t stream) {
  const float* query  = (const float*)d_in[0];
  const float* values = (const float*)d_in[1];
  const float* W1     = (const float*)d_in[2];
  const float* b1     = (const float*)d_in[3];
  const float* W2     = (const float*)d_in[4];
  const float* b2     = (const float*)d_in[5];
  const float* V      = (const float*)d_in[6];
  // d_in[7] = bV: uniform score shift -> softmax-invariant, dropped.

  float* ctx  = (float*)d_out;             // [B,D]
  float* attn = (float*)d_out + BB * DD;   // [B,T,1]

  // ws: qb 64KB | score 256KB | w1a 512KB | o_part 2MB | l_part 4KB
  float* qb           = (float*)d_ws;                        // [B,U]
  float* score        = qb + BB * UU;                        // [B*T]
  unsigned short* w1a = (unsigned short*)(score + BB * TT);  // 512KB bf16
  float* o_part       = (float*)(w1a + (size_t)UU * DD);     // [1024][512]
  float* l_part       = o_part + (size_t)1024 * DD;          // [1024]

  prep_kernel<<<128, 256, 0, stream>>>(W1, w1a, query, W2, b2, b1, qb);

  score_fused_kernel<<<(BB * TT) / SBM, 512, 0, stream>>>(
      values, w1a, qb, V, score, o_part, l_part);

  finish_kernel<<<96, 128, 0, stream>>>(o_part, l_part, score, ctx, attn);
}